// Round 8
// baseline (1144.582 us; speedup 1.0000x reference)
//
#include <hip/hip_runtime.h>
#include <hip/hip_bf16.h>
#include <cstdint>
#include <cstddef>

// Problem constants
#define NP     100352      // 32*56*56 total pixels
#define HW     3136        // 56*56
#define CDIM   384
#define C3     1152        // 3*384
#define NHEAD  12
#define HD     32          // head dim
#define NWIN   2048        // 32 * 8 * 8 windows

typedef __attribute__((ext_vector_type(8))) short bf16x8;
typedef __attribute__((ext_vector_type(4))) float f32x4;

static __device__ __forceinline__ unsigned short f2bf(float f) {
    union { float f; uint32_t i; } v; v.f = f;
    uint32_t r = v.i + 0x7FFFu + ((v.i >> 16) & 1u);   // round-nearest-even
    return (unsigned short)(r >> 16);
}
// pack two f32 -> bf16 pair (round-half-up; lo half = a)
static __device__ __forceinline__ uint32_t pk2(float a, float b) {
    union { float f; uint32_t u; } x, y; x.f = a; y.f = b;
    return ((x.u + 0x8000u) >> 16) | ((y.u + 0x8000u) & 0xffff0000u);
}

// async global->LDS, 16B per lane; LDS dest = WAVE-UNIFORM base + lane*16
static __device__ __forceinline__ void gld_lds16(const void* g, void* l) {
    __builtin_amdgcn_global_load_lds(
        (const __attribute__((address_space(1))) void*)g,
        (__attribute__((address_space(3))) void*)l, 16, 0, 0);
}

// ---------------------------------------------------------------------------
// Kernel 1 (fused prep):
// blocks [0,432):   w_qkv f32->bf16, rows permuted HEAD-MAJOR:
//                   dst row h*96 + {0..31 Q | 32..63 K | 64..95 V} of head h
// blocks [432,576): w_proj f32->bf16 (unchanged layout)
// blocks [576,768): bias_t[h][query][key] fp32 64x64 padded (-1e30 pads)
// blocks [768,10176): transpose x (B,C,HW) f32 -> xt WINDOW-MAJOR:
//                   row p' = win*49 + tok (win = b*64+wy*8+wx, tok = r*7+cc),
//                   256-B uint4 bursts per row (same burst size as before).
// ---------------------------------------------------------------------------
__global__ __launch_bounds__(256) void prep_transpose(
    const float* __restrict__ x, const float* __restrict__ w_qkv,
    const float* __restrict__ w_proj, const float* __restrict__ btab,
    unsigned short* __restrict__ wqb, unsigned short* __restrict__ wpb,
    float* __restrict__ bias_t, unsigned short* __restrict__ xt) {
    int bid = blockIdx.x;
    int tid = threadIdx.x;
    if (bid < 432) {                         // w_qkv cvt + head-major permute
        int i = bid * 256 + tid;             // float4 index; row = i/96
        int row = i / 96, c4 = i - row * 96;
        int rp;
        if (row < 384)      rp = (row >> 5) * 96 + (row & 31);
        else if (row < 768) { int rr = row - 384; rp = (rr >> 5) * 96 + 32 + (rr & 31); }
        else                { int rr = row - 768; rp = (rr >> 5) * 96 + 64 + (rr & 31); }
        float4 v = ((const float4*)w_qkv)[i];
        ushort4 r;
        r.x = f2bf(v.x); r.y = f2bf(v.y); r.z = f2bf(v.z); r.w = f2bf(v.w);
        ((ushort4*)wqb)[rp * 96 + c4] = r;
    } else if (bid < 576) {                  // w_proj cvt
        int i = (bid - 432) * 256 + tid;     // 144*256 = 36864 exactly
        float4 v = ((const float4*)w_proj)[i];
        ushort4 r;
        r.x = f2bf(v.x); r.y = f2bf(v.y); r.z = f2bf(v.z); r.w = f2bf(v.w);
        ((ushort4*)wpb)[i] = r;
    } else if (bid < 768) {                  // bias precompute
        int idx = (bid - 576) * 256 + tid;   // 192*256 = 49152
        int h = idx >> 12, query = (idx >> 6) & 63, key = idx & 63;
        float v = -1e30f;
        if (query < 49 && key < 49) {
            int ri = query / 7, rj = query % 7, mi = key / 7, mj = key % 7;
            v = btab[((ri - mi + 6) * 13 + (rj - mj + 6)) * NHEAD + h] * 5.656854249492381f;
        }
        bias_t[idx] = v;
    } else {                                 // transpose tile -> window-major xt
        __shared__ unsigned short tile[32][136];   // 272-B rows: 16-B aligned
        int t  = bid - 768;                  // 9408 tiles = 32 b * 3 c * 98 hw
        int b  = t / 294;
        int r  = t - b * 294;
        int c0  = (r / 98) * 128;
        int hw0 = (r % 98) * 32;
        int tx = tid & 31, ty = tid >> 5;    // ty 0..7
        const float* xp = x + ((size_t)b * CDIM + c0) * HW + hw0;
#pragma unroll
        for (int i = 0; i < 16; i++) {
            int c = i * 8 + ty;              // 0..127
            tile[tx][c] = f2bf(xp[(size_t)c * HW + tx]);   // coalesced read along hw
        }
        __syncthreads();
        int row2 = tid >> 4, seg = tid & 15; // 16 rows/pass, uint4 seg
#pragma unroll
        for (int pass = 0; pass < 2; pass++) {
            int row = pass * 16 + row2;      // local hw
            int hw = hw0 + row;
            int y = hw / 56, xc = hw - y * 56;
            int wy = y / 7, rr = y - wy * 7;
            int wx = xc / 7, cc = xc - wx * 7;
            int pp = ((b << 6) + (wy << 3) + wx) * 49 + rr * 7 + cc;
            uint4 v = *(const uint4*)(&tile[row][seg * 8]);
            *(uint4*)(xt + (size_t)pp * CDIM + c0 + seg * 8) = v;   // 256-B burst
        }
    }
}

// ---------------------------------------------------------------------------
// Fused qkv-GEMM + window attention. grid 2048 (1 window/block), 256 thr
// (4 waves; wave w owns tokens w*16..w*16+15 = its query rows).
// Phase 0: stage window's 49x384 A-panel to LDS (coalesced gld_lds), zero
//          pad rows 49..63, hoist 12 A-frags/wave to regs (one-shot; the
//          16-way-conflict LDS read happens once, negligible).
// Per head h (12x):
//   GEMM 64x96x384: acc[6] (16 tokens x 96 cols QKV); B-frags per-lane
//   straight from L2-resident head-major wqb (no barriers in GEMM loop).
//   Share: Q,K -> sQ/sK[64][40] (80-B stride: frag reads 2-way = free),
//   V^T -> sVT[32][72]; pads are exact zeros (A pad rows zeroed).
//   barrier. Attention per wave (16 queries): S^T = mfma(K, Q) + bias
//   (-1e30 pads = free masking), shfl softmax over keys, P -> sP[64][72],
//   O^T = mfma(V^T, P); store O direct to outt (hw-major pixel rows).
//   barrier (WAR on shares).
// LDS 73.2 KB -> 2 blocks/CU. Eliminates the 231 MB qkvt write + 231 MB read.
// ---------------------------------------------------------------------------
__global__ __launch_bounds__(256, 2) void qkv_attn(
    const unsigned short* __restrict__ xt,   // window-major [2048*49][384]
    const unsigned short* __restrict__ wqb,  // head-major [12*96][384]
    const float* __restrict__ bias_t,        // [12][64][64]
    unsigned short* __restrict__ outt) {     // hw-major [NP][384]
    __shared__ __align__(16) unsigned short sA[64 * 384];   // 49,152 B
    __shared__ __align__(16) unsigned short sQ[64 * 40];    //  5,120 B
    __shared__ __align__(16) unsigned short sK[64 * 40];    //  5,120 B
    __shared__ __align__(16) unsigned short sVT[32 * 72];   //  4,608 B
    __shared__ __align__(16) unsigned short sP[64 * 72];    //  9,216 B

    int w = blockIdx.x, tid = threadIdx.x;
    int wv = tid >> 6, lane = tid & 63;
    int lq = lane >> 4, lr = lane & 15;

    // stage A: 49 rows x 768 B contiguous = 2352 16-B chunks, linear LDS
    const unsigned short* srcA = xt + (size_t)w * 49 * 384;
#pragma unroll
    for (int pass = 0; pass < 10; pass++) {
        int c = pass * 256 + tid;
        if (c < 2352) gld_lds16(srcA + c * 8, sA + c * 8);
    }
    for (int i = tid; i < 720; i += 256)     // zero pad rows 49..63
        ((uint4*)(sA + 49 * 384))[i] = (uint4){0u, 0u, 0u, 0u};
    __syncthreads();

    // hoist this wave's A-frags (rows wv*16+lr, all 12 K-steps)
    bf16x8 afr[12];
#pragma unroll
    for (int kt = 0; kt < 12; kt++)
        afr[kt] = *(const bf16x8*)(sA + (wv * 16 + lr) * 384 + kt * 32 + lq * 8);

    // this lane's query token (C col = lr) -> pixel for O store
    int tokq = wv * 16 + lr;
    int valid = tokq < 49;
    int tc = valid ? tokq : 0;
    int b = w >> 6, wy = (w >> 3) & 7, wx = w & 7;
    int pix = b * HW + (wy * 7 + tc / 7) * 56 + wx * 7 + (tc % 7);
    const float KSC = 0.25503472f;           // 2^-2.5 * log2(e)

    for (int h = 0; h < 12; h++) {
        // ---------------- GEMM: 16 tokens x 96 head-cols ----------------
        f32x4 acc[6];
#pragma unroll
        for (int nt = 0; nt < 6; nt++) acc[nt] = (f32x4){0.f, 0.f, 0.f, 0.f};
        const unsigned short* bh = wqb + (size_t)h * 96 * 384;
#pragma unroll
        for (int kt = 0; kt < 12; kt++) {
            bf16x8 bfr[6];
#pragma unroll
            for (int nt = 0; nt < 6; nt++)
                bfr[nt] = *(const bf16x8*)(bh + (size_t)(nt * 16 + lr) * 384 + kt * 32 + lq * 8);
#pragma unroll
            for (int nt = 0; nt < 6; nt++)
                acc[nt] = __builtin_amdgcn_mfma_f32_16x16x32_bf16(
                    afr[kt], bfr[nt], acc[nt], 0, 0, 0);
        }
        // ---------------- share Q, K, V^T via LDS ----------------
        // lane holds tokens wv*16+lq*4+i, col nt*16+lr
#pragma unroll
        for (int i = 0; i < 4; i++) {
            int t = wv * 16 + lq * 4 + i;
            sQ[t * 40 + lr]          = f2bf(acc[0][i]);
            sQ[t * 40 + 16 + lr]     = f2bf(acc[1][i]);
            sK[t * 40 + lr]          = f2bf(acc[2][i]);
            sK[t * 40 + 16 + lr]     = f2bf(acc[3][i]);
            sVT[lr * 72 + t]         = f2bf(acc[4][i]);
            sVT[(16 + lr) * 72 + t]  = f2bf(acc[5][i]);
        }
        __syncthreads();
        // ---------------- attention (wave's 16 queries) ----------------
        bf16x8 qf = *(const bf16x8*)(sQ + (wv * 16 + lr) * 40 + lq * 8);
        bf16x8 kf[4];
#pragma unroll
        for (int mt = 0; mt < 4; mt++)
            kf[mt] = *(const bf16x8*)(sK + (mt * 16 + lr) * 40 + lq * 8);
        // S^T acc init = bias_t[h][query][key] (pads -1e30 -> free masking)
        f32x4 sv[4];
        const float* bp = bias_t + h * 4096 + (wv * 16 + lr) * 64 + lq * 4;
#pragma unroll
        for (int mt = 0; mt < 4; mt++) sv[mt] = *(const f32x4*)(bp + 16 * mt);
#pragma unroll
        for (int mt = 0; mt < 4; mt++)
            sv[mt] = __builtin_amdgcn_mfma_f32_16x16x32_bf16(kf[mt], qf, sv[mt], 0, 0, 0);
        // softmax over keys (lane's 16 vals + shfl across lq groups)
        float mx = sv[0][0];
#pragma unroll
        for (int mt = 0; mt < 4; mt++)
#pragma unroll
            for (int i = 0; i < 4; i++) mx = fmaxf(mx, sv[mt][i]);
        mx = fmaxf(mx, __shfl_xor(mx, 16));
        mx = fmaxf(mx, __shfl_xor(mx, 32));
        float sum = 0.f;
#pragma unroll
        for (int mt = 0; mt < 4; mt++)
#pragma unroll
            for (int i = 0; i < 4; i++) {
                float e = exp2f((sv[mt][i] - mx) * KSC);
                sv[mt][i] = e; sum += e;
            }
        sum += __shfl_xor(sum, 16);
        sum += __shfl_xor(sum, 32);
        float inv = 1.0f / sum;
#pragma unroll
        for (int mt = 0; mt < 4; mt++) {
            uint32_t u01 = pk2(sv[mt][0] * inv, sv[mt][1] * inv);
            uint32_t u23 = pk2(sv[mt][2] * inv, sv[mt][3] * inv);
            *(uint2*)(sP + (wv * 16 + lr) * 72 + 4 * lq + 16 * mt) = make_uint2(u01, u23);
        }
        // PV: O^T[d][query]
        bf16x8 pf[2], vf[2][2];
#pragma unroll
        for (int ks = 0; ks < 2; ks++)
            pf[ks] = *(const bf16x8*)(sP + (wv * 16 + lr) * 72 + lq * 8 + 32 * ks);
#pragma unroll
        for (int mt = 0; mt < 2; mt++)
#pragma unroll
            for (int ks = 0; ks < 2; ks++)
                vf[mt][ks] = *(const bf16x8*)(sVT + (mt * 16 + lr) * 72 + lq * 8 + 32 * ks);
        f32x4 oa[2];
        oa[0] = (f32x4){0.f, 0.f, 0.f, 0.f};
        oa[1] = (f32x4){0.f, 0.f, 0.f, 0.f};
#pragma unroll
        for (int ks = 0; ks < 2; ks++)
#pragma unroll
            for (int mt = 0; mt < 2; mt++)
                oa[mt] = __builtin_amdgcn_mfma_f32_16x16x32_bf16(
                    vf[mt][ks], pf[ks], oa[mt], 0, 0, 0);
        if (valid) {
            unsigned short* dst = outt + (size_t)pix * CDIM + h * HD + 4 * lq;
            *(uint2*)(dst)      = make_uint2(pk2(oa[0][0], oa[0][1]), pk2(oa[0][2], oa[0][3]));
            *(uint2*)(dst + 16) = make_uint2(pk2(oa[1][0], oa[1][1]), pk2(oa[1][2], oa[1][3]));
        }
        __syncthreads();   // WAR guard before next head overwrites shares
    }
}

// ---------------------------------------------------------------------------
// 8-phase MFMA GEMM core (R4 structure) — used by gemm_proj8 only now.
// ---------------------------------------------------------------------------
template<int BM, int BN, int WM, int WN>
static __device__ __forceinline__ void gemm8(
    const unsigned short* __restrict__ A, const unsigned short* __restrict__ Bt,
    int m0, int n0, unsigned short* lds, f32x4 acc[4][4]) {

    constexpr int NA   = BM / 64;
    constexpr int BUFE = (BM + BN) * 64;

    const int tid  = threadIdx.x;
    const int wv   = tid >> 6;
    const int lane = tid & 63;
    const int wc = wv & (WN - 1), wr = wv / WN;
    const int lrow = lane & 15, lq = lane >> 4;
    const int lr8  = lane >> 3;
    const int gsl  = ((lane & 7) ^ lr8) << 3;

#pragma unroll
    for (int i = 0; i < 4; i++)
#pragma unroll
        for (int j = 0; j < 4; j++) acc[i][j] = (f32x4){0.f, 0.f, 0.f, 0.f};

    auto stage = [&](int s, int kt, int bufi) {
        if (s < NA) {
            int grow = m0 + s * 64 + wv * 8 + lr8;
            gld_lds16(A + (size_t)grow * 384 + kt * 64 + gsl,
                      lds + bufi * BUFE + (s * 8 + wv) * 512);
        } else {
            int sj = s - NA;
            int grow = n0 + sj * 64 + wv * 8 + lr8;
            gld_lds16(Bt + (size_t)grow * 384 + kt * 64 + gsl,
                      lds + bufi * BUFE + BM * 64 + (sj * 8 + wv) * 512);
        }
    };

#pragma unroll
    for (int s = 0; s < 6; s++) stage(s, 0, 0);
#pragma unroll
    for (int s = 0; s < 6; s++) stage(s, 1, 1);

#pragma unroll
    for (int t = 0; t < 6; t++) {
        const int bufi = t % 3, nbuf = (t + 2) % 3;
        const unsigned short* la = lds + bufi * BUFE;
        const unsigned short* lb = la + BM * 64;
        bf16x8 af[4][2], bfr[2][2];

        if (t < 4) { stage(0, t + 2, nbuf); stage(1, t + 2, nbuf); stage(2, t + 2, nbuf); }
        if (t < 4)       asm volatile("s_waitcnt vmcnt(9)" ::: "memory");
        else if (t == 4) asm volatile("s_waitcnt vmcnt(6)" ::: "memory");
        else             asm volatile("s_waitcnt vmcnt(0)" ::: "memory");
        __builtin_amdgcn_sched_barrier(0);
        __builtin_amdgcn_s_barrier();

#pragma unroll
        for (int mi = 0; mi < 4; mi++)
#pragma unroll
            for (int ks = 0; ks < 2; ks++)
                af[mi][ks] = *(const bf16x8*)(la + (wr * 64 + mi * 16 + lrow) * 64 +
                                              (((ks * 4 + lq) ^ (lrow & 7)) << 3));
#pragma unroll
        for (int ni = 0; ni < 2; ni++)
#pragma unroll
            for (int ks = 0; ks < 2; ks++)
                bfr[ni][ks] = *(const bf16x8*)(lb + (wc * 64 + ni * 16 + lrow) * 64 +
                                               (((ks * 4 + lq) ^ (lrow & 7)) << 3));
        __builtin_amdgcn_s_setprio(1);
#pragma unroll
        for (int mi = 0; mi < 4; mi++)
#pragma unroll
            for (int ni = 0; ni < 2; ni++)
#pragma unroll
                for (int ks = 0; ks < 2; ks++)
                    acc[mi][ni] = __builtin_amdgcn_mfma_f32_16x16x32_bf16(
                        af[mi][ks], bfr[ni][ks], acc[mi][ni], 0, 0, 0);
        __builtin_amdgcn_s_setprio(0);
        __builtin_amdgcn_s_barrier();

        if (t < 4) { stage(3, t + 2, nbuf); stage(4, t + 2, nbuf); stage(5, t + 2, nbuf); }
        __builtin_amdgcn_s_barrier();
#pragma unroll
        for (int ni = 0; ni < 2; ni++)
#pragma unroll
            for (int ks = 0; ks < 2; ks++)
                bfr[ni][ks] = *(const bf16x8*)(lb + (wc * 64 + (ni + 2) * 16 + lrow) * 64 +
                                               (((ks * 4 + lq) ^ (lrow & 7)) << 3));
        __builtin_amdgcn_s_setprio(1);
#pragma unroll
        for (int mi = 0; mi < 4; mi++)
#pragma unroll
            for (int ni = 0; ni < 2; ni++)
#pragma unroll
                for (int ks = 0; ks < 2; ks++)
                    acc[mi][ni + 2] = __builtin_amdgcn_mfma_f32_16x16x32_bf16(
                        af[mi][ks], bfr[ni][ks], acc[mi][ni + 2], 0, 0, 0);
        __builtin_amdgcn_s_setprio(0);
        __builtin_amdgcn_s_barrier();
    }
}

// GEMM 2: out[b][o][hw] = sum_c w_proj[o][c] * out_t[p][c] + b_proj[o]
// BM=128 (o), BN=256 (p): grid 1176 = 8*147. LDS-staged f32 coalesced
// epilogue (float4 1-KB bursts along hw; 3136%4==0 so no batch straddle).
__global__ __launch_bounds__(512) void gemm_proj8(
    const unsigned short* __restrict__ A, const unsigned short* __restrict__ Bt,
    const float* __restrict__ bias, float* __restrict__ out) {
    __shared__ __align__(16) unsigned short lds[3 * (128 + 256) * 64];  // 144 KiB
    int lin = blockIdx.x;
    int xcd = lin & 7, pos = lin >> 3;
    int nid = xcd * 147 + pos;              // bijective: 1176 = 8*147
    int m0 = (nid % 3) * 128;
    int n0 = (nid / 3) * 256;
    f32x4 acc[4][4];
    gemm8<128, 256, 2, 4>(A, Bt, m0, n0, lds, acc);

    int lane = threadIdx.x & 63, wv = threadIdx.x >> 6;
    int wc = wv & 3, wr = wv >> 2;
    int lrow = lane & 15, lq = lane >> 4;

    float* sCf = (float*)lds;
#pragma unroll
    for (int mi = 0; mi < 4; mi++)
#pragma unroll
        for (int ni = 0; ni < 4; ni++)
#pragma unroll
            for (int i = 0; i < 4; i++) {
                int row = wr * 64 + mi * 16 + lq * 4 + i;   // local o
                int col = wc * 64 + ni * 16 + lrow;         // local p
                sCf[row * 256 + col] = acc[mi][ni][i] + bias[m0 + row];
            }
    __syncthreads();
    int r0   = threadIdx.x >> 6;   // 0..7
    int slot = threadIdx.x & 63;   // float4 slot
#pragma unroll
    for (int pass = 0; pass < 16; pass++) {
        int row = pass * 8 + r0;               // local o
        int p4  = n0 + slot * 4;               // global pixel (4-aligned)
        int b   = p4 / HW, hw = p4 - b * HW;   // float4 never straddles b
        float4 v = *(const float4*)(sCf + row * 256 + slot * 4);
        *(float4*)(out + (size_t)b * CDIM * HW + (size_t)(m0 + row) * HW + hw) = v;
    }
}

// ---------------------------------------------------------------------------
// Launch (3 kernels)
// ---------------------------------------------------------------------------
extern "C" void kernel_launch(void* const* d_in, const int* in_sizes, int n_in,
                              void* d_out, int out_size, void* d_ws, size_t ws_size,
                              hipStream_t stream) {
    const float* x      = (const float*)d_in[0];
    const float* w_qkv  = (const float*)d_in[1];
    const float* btab   = (const float*)d_in[2];
    const float* w_proj = (const float*)d_in[3];
    const float* b_proj = (const float*)d_in[4];
    float* out = (float*)d_out;

    // workspace layout (bytes)
    char* ws = (char*)d_ws;
    const size_t off_xt   = 0;                         // 77,070,336 (window-major xt)
    const size_t off_ot   = 77070336;                  // outt (77 MB of old qkv region)
    const size_t off_wq   = off_ot + 231211008;        // 884,736
    const size_t off_wp   = off_wq + 884736;           // 294,912
    const size_t off_bt   = off_wp + 294912;           // 196,608
    unsigned short* xt   = (unsigned short*)(ws + off_xt);
    unsigned short* outt = (unsigned short*)(ws + off_ot);  // NOT aliased with xt:
    unsigned short* wqb  = (unsigned short*)(ws + off_wq);  // fused kernel reads xt
    unsigned short* wpb  = (unsigned short*)(ws + off_wp);  // while writing outt
    float*          bt   = (float*)(ws + off_bt);

    prep_transpose<<<10176, 256, 0, stream>>>(x, w_qkv, w_proj, btab, wqb, wpb, bt, xt);
    qkv_attn<<<NWIN, 256, 0, stream>>>(xt, wqb, bt, outt);
    gemm_proj8<<<1176, 512, 0, stream>>>(wpb, outt, b_proj, out);
}